// Round 8
// baseline (191.192 us; speedup 1.0000x reference)
//
#include <hip/hip_runtime.h>
#include <hip/hip_bf16.h>
#include <math.h>

#define CC   256
#define NQQ  4096
#define MT   8192

typedef __attribute__((ext_vector_type(8))) short s8v;
typedef __attribute__((ext_vector_type(4))) float f4v;

static __device__ __forceinline__ ushort f2bu(float f) {
    __hip_bfloat16 h = __float2bfloat16(f);
    return *reinterpret_cast<ushort*>(&h);
}

// Fragment layout for weights: Wf[((ntile*8 + kc)*64 + lane)*8 + e]
//   lane l supplies B rows (n = ntile*16 + (l&15)), k = kc*32 + (l>>4)*8 + e
// => a wave's fragment load is 64 lanes x 16B contiguous (1KB), fully coalesced.

// ======== setup: pos/refpts/tgt-init + weight->fragment transpose + fuse ========
__global__ __launch_bounds__(256) void setup_kernel(
        const float* __restrict__ qemb, const float* __restrict__ rw,
        const float* __restrict__ rb,
        const float* __restrict__ feat0, const float* __restrict__ feat1,
        const float* __restrict__ fl,
        const float* __restrict__ val_w, const float* __restrict__ off_w,
        const float* __restrict__ aw_w,  const float* __restrict__ out_w,
        const float* __restrict__ f1_w,  const float* __restrict__ f2_w,
        const float* __restrict__ off_b, const float* __restrict__ aw_b,
        float* __restrict__ pos, float* __restrict__ refp, float* __restrict__ tgt,
        ushort* __restrict__ wval01, ushort* __restrict__ wvalS,
        ushort* __restrict__ woffaw, ushort* __restrict__ wout,
        ushort* __restrict__ wf1, ushort* __restrict__ wf2,
        float* __restrict__ bOA, ushort* __restrict__ fused) {
    __shared__ float tl[64][65];
    int bid = blockIdx.x;
    int t = threadIdx.x;
    if (bid < 2048) {                       // pos
        int idx = bid * 256 + t;
        int q = idx >> 7, pp = idx & 127;
        int p = pp >> 6, u = pp & 63;
        float coordbase = (p == 0) ? (float)((q >> 6) + 1) : (float)((q & 63) + 1);
        float coord = coordbase * (6.28318530717958647692f / (64.0f + 1e-6f));
        float v = coord * exp2f(-0.20762050593046016f * (float)u);
        *(float2*)(pos + (size_t)q * 256 + p * 128 + u * 2) = make_float2(__sinf(v), __cosf(v));
        return;
    }
    if (bid < 3072) {                       // refpts
        int row = (bid - 2048) * 4 + (t >> 6);
        int l = t & 63;
        float4 v = *(const float4*)(qemb + (size_t)row * 512 + l * 4);
        float a0 = v.x * rw[(l * 4 + 0) * 2] + v.y * rw[(l * 4 + 1) * 2]
                 + v.z * rw[(l * 4 + 2) * 2] + v.w * rw[(l * 4 + 3) * 2];
        float a1 = v.x * rw[(l * 4 + 0) * 2 + 1] + v.y * rw[(l * 4 + 1) * 2 + 1]
                 + v.z * rw[(l * 4 + 2) * 2 + 1] + v.w * rw[(l * 4 + 3) * 2 + 1];
        #pragma unroll
        for (int o = 32; o > 0; o >>= 1) { a0 += __shfl_xor(a0, o); a1 += __shfl_xor(a1, o); }
        if (l == 0) {
            refp[row * 2 + 0] = 1.0f / (1.0f + __expf(-(a0 + rb[0])));
            refp[row * 2 + 1] = 1.0f / (1.0f + __expf(-(a1 + rb[1])));
        }
        return;
    }
    if (bid < 5120) {                       // tgt init
        int idx = (bid - 3072) * 256 + t;
        int c4 = idx & 63;
        int q = (idx >> 6) & (NQQ - 1);
        *(float4*)(tgt + (size_t)idx * 4) = *(const float4*)(qemb + (size_t)q * 512 + 256 + c4 * 4);
        return;
    }
    if (bid < 5428) {                       // weight prep -> fragment layout
        int wb = bid - 5120;
        if (wb >= 304) {
            int layer = wb - 304;
            if (t < 192)
                bOA[layer * 192 + t] = (t < 128) ? off_b[layer * 128 + t]
                                                 : aw_b[layer * 64 + (t - 128)];
            return;
        }
        const float* src; ushort* dstF; int srcStride, ntb, kcb;
        if (wb < 32) {
            int nt = wb & 7, kt = wb >> 3;
            int layer = nt >> 2, nn = (nt & 3) * 64;
            src = val_w + (size_t)layer * 65536 + (size_t)kt * 64 * 256 + nn; srcStride = 256;
            dstF = wval01; ntb = nt * 4; kcb = kt * 2;
        } else if (wb < 64) {
            int b = wb - 32; int layer = b >> 4; int kt = (b >> 2) & 3; int nt = b & 3;
            src = val_w + (size_t)(2 + layer) * 65536 + (size_t)kt * 64 * 256 + nt * 64; srcStride = 256;
            dstF = wvalS + (size_t)layer * 65536; ntb = nt * 4; kcb = kt * 2;
        } else if (wb < 112) {
            int b = wb - 64; int layer = b / 12; int rem = b % 12; int kt = rem / 3; int nt = rem % 3;
            if (nt < 2) { src = off_w + (size_t)layer * 256 * 128 + (size_t)kt * 64 * 128 + nt * 64; srcStride = 128; }
            else        { src = aw_w  + (size_t)layer * 256 * 64  + (size_t)kt * 64 * 64;            srcStride = 64;  }
            dstF = woffaw + (size_t)layer * 49152; ntb = nt * 4; kcb = kt * 2;
        } else {
            int b = wb - 112; int fam = b >> 6; int bb = b & 63;
            int layer = bb >> 4; int kt = (bb >> 2) & 3; int nt = bb & 3;
            const float* s0 = (fam == 0) ? out_w : ((fam == 1) ? f1_w : f2_w);
            ushort* d0      = (fam == 0) ? wout  : ((fam == 1) ? wf1  : wf2);
            src = s0 + (size_t)layer * 65536 + (size_t)kt * 64 * 256 + nt * 64; srcStride = 256;
            dstF = d0 + (size_t)layer * 65536; ntb = nt * 4; kcb = kt * 2;
        }
        int r = t >> 6, c = t & 63;
        #pragma unroll
        for (int rr = 0; rr < 64; rr += 4)                 // tl[k_local][n_local]
            tl[rr + r][c] = src[(size_t)(rr + r) * srcStride + c];
        __syncthreads();
        int l = t >> 2;               // 0..63 (lane of fragment)
        int e0 = (t & 3) * 2;         // 0,2,4,6
        int frow = l & 15;            // n within 16-tile
        int fcol = (l >> 4) * 8;      // k offset within chunk
        #pragma unroll
        for (int s = 0; s < 8; s++) {
            int ntl = s & 3, kcl = s >> 2;
            int ntile = ntb + ntl, kc = kcb + kcl;
            ushort2 val;
            val.x = f2bu(tl[kcl * 32 + fcol + e0    ][ntl * 16 + frow]);
            val.y = f2bu(tl[kcl * 32 + fcol + e0 + 1][ntl * 16 + frow]);
            *(ushort2*)(dstF + (((size_t)ntile * 8 + kc) * 64 + l) * 8 + e0) = val;
        }
        return;
    }
    {                                       // fuse
        int fb = bid - 5428;
        int b = fb >> 8;
        int c0 = ((fb >> 6) & 3) * 64;
        int q0 = (fb & 63) * 64;
        int r = t >> 6, c = t & 63;
        #pragma unroll
        for (int rr = 0; rr < 64; rr += 4) {
            int ch = c0 + rr + r;
            float l0 = fl[ch], l1 = fl[CC + ch];
            float m = fmaxf(l0, l1);
            float e0 = __expf(l0 - m), e1 = __expf(l1 - m);
            float inv = 1.0f / (e0 + e1);
            size_t o = ((size_t)b * CC + ch) * NQQ + q0 + c;
            tl[rr + r][c] = (feat0[o] * e0 + feat1[o] * e1) * inv;
        }
        __syncthreads();
        #pragma unroll
        for (int rr = 0; rr < 64; rr += 4)
            fused[((size_t)(b * NQQ + q0 + rr + r)) * CC + c0 + c] = f2bu(tl[c][rr + r]);
    }
}

// ======== projection GEMM: 16-row tiles, 512 threads, fragment-B ========
template<int ASRC, int NTJ>
__global__ __launch_bounds__(512) void pgemm(const ushort* __restrict__ Abf,
        const float* __restrict__ Af, const ushort* __restrict__ Wf,
        const float* __restrict__ bias, ushort* __restrict__ Cb, int NS) {
    __shared__ ushort Abuf[16 * 264];
    const int t = threadIdx.x;
    const int m0 = blockIdx.x * 16;
    const int cb0 = blockIdx.y * 256;
    const int ntb = blockIdx.y * 16;
    {
        const int rg = t >> 5, c0 = (t & 31) * 8;
        ushort* dst = Abuf + rg * 264 + c0;
        if (ASRC == 0) {
            *(int4*)dst = *(const int4*)(Abf + (size_t)(m0 + rg) * 256 + c0);
        } else {
            const float* src = Af + (size_t)(m0 + rg) * 256 + c0;
            ushort tmp[8];
            #pragma unroll
            for (int j = 0; j < 2; j++) {
                float4 v = *(const float4*)(src + j * 4);
                tmp[j * 4 + 0] = f2bu(v.x); tmp[j * 4 + 1] = f2bu(v.y);
                tmp[j * 4 + 2] = f2bu(v.z); tmp[j * 4 + 3] = f2bu(v.w);
            }
            *(int4*)dst = *(const int4*)tmp;
        }
    }
    __syncthreads();
    const int l = t & 63, w = t >> 6;
    const int fr = l & 15, fk8 = (l >> 4) * 8, rb = (l >> 4) * 4;
    f4v acc[NTJ] = {};
    #pragma unroll
    for (int kc = 0; kc < 8; kc++) {
        s8v a = *(const s8v*)(Abuf + fr * 264 + kc * 32 + fk8);
        #pragma unroll
        for (int j = 0; j < NTJ; j++) {
            int nt = ntb + j * 8 + w;
            s8v b = *(const s8v*)(Wf + (((size_t)nt * 8 + kc) * 64 + l) * 8);
            acc[j] = __builtin_amdgcn_mfma_f32_16x16x32_bf16(a, b, acc[j], 0, 0, 0);
        }
    }
    #pragma unroll
    for (int j = 0; j < NTJ; j++) {
        int gcol = cb0 + (j * 8 + w) * 16 + fr;
        float bz = bias[gcol];
        #pragma unroll
        for (int r = 0; r < 4; r++)
            Cb[(size_t)(m0 + rb + r) * NS + gcol] = f2bu(acc[j][r] + bz);
    }
}

// ======== full decoder layer: 16 rows/block, 1024 threads (16 waves), 100% occ ========
// SELF: query source; EMITVAL: append value projection for the NEXT layer from final tgt.
template<int SELF, int EMITVAL>
__global__ __launch_bounds__(1024, 8) void layer_kernel(
        float* __restrict__ tgt, const float* __restrict__ posq,
        const float* __restrict__ g1, const float* __restrict__ b1,
        const ushort* __restrict__ woffawL, const float* __restrict__ bOAL,
        const ushort* __restrict__ value, int vstride,
        const float* __restrict__ refp,
        const ushort* __restrict__ woutL, const float* __restrict__ out_bL,
        const float* __restrict__ g2, const float* __restrict__ b2,
        const ushort* __restrict__ wf1L, const float* __restrict__ f1_bL,
        const ushort* __restrict__ wf2L, const float* __restrict__ f2_bL,
        const ushort* __restrict__ wvalN, const float* __restrict__ val_bN,
        ushort* __restrict__ valueOut) {
    __shared__ ushort Abuf[16 * 264];
    __shared__ float Slds[16 * 204];
    __shared__ float pred[2][16][16];
    const int t = threadIdx.x;
    const int l = t & 63, w = t >> 6;           // wave = 0..15
    const int m0 = blockIdx.x * 16;

    // ---- phase 0: stage query tile, wave per row ----
    {
        const int c0 = l * 4;
        int m = m0 + w, q = m & (NQQ - 1);
        const float* src = tgt + (size_t)m * 256 + c0;
        float4 fv = *(const float4*)src;
        if (!SELF) {
            float s = fv.x + fv.y + fv.z + fv.w;
            #pragma unroll
            for (int o = 32; o > 0; o >>= 1) s += __shfl_xor(s, o);
            float mean = s * (1.0f / 256.0f);
            float dx = fv.x - mean, dy = fv.y - mean, dz = fv.z - mean, dw = fv.w - mean;
            float s2 = dx * dx + dy * dy + dz * dz + dw * dw;
            #pragma unroll
            for (int o = 32; o > 0; o >>= 1) s2 += __shfl_xor(s2, o);
            float rstd = rsqrtf(s2 * (1.0f / 256.0f) + 1e-5f);
            float4 gv = *(const float4*)(g1 + c0);
            float4 bv = *(const float4*)(b1 + c0);
            float4 ev = *(const float4*)(posq + (size_t)q * 512 + c0);   // qemb[:, :C]
            fv.x = dx * rstd * gv.x + bv.x + ev.x;
            fv.y = dy * rstd * gv.y + bv.y + ev.y;
            fv.z = dz * rstd * gv.z + bv.z + ev.z;
            fv.w = dw * rstd * gv.w + bv.w + ev.w;
        } else {
            float4 ev = *(const float4*)(posq + (size_t)q * 256 + c0);
            fv.x += ev.x; fv.y += ev.y; fv.z += ev.z; fv.w += ev.w;
        }
        ushort4 pk;
        pk.x = f2bu(fv.x); pk.y = f2bu(fv.y); pk.z = f2bu(fv.z); pk.w = f2bu(fv.w);
        *(ushort4*)(Abuf + w * 264 + c0) = pk;
    }
    __syncthreads();

    const int fr = l & 15, fk8 = (l >> 4) * 8, rb = (l >> 4) * 4;

    // ---- phase 1: offaw GEMM (12 n-tiles, waves 0..11) ----
    if (w < 12) {
        f4v oacc = {};
        #pragma unroll
        for (int kc = 0; kc < 8; kc++) {
            s8v a = *(const s8v*)(Abuf + fr * 264 + kc * 32 + fk8);
            s8v b = *(const s8v*)(woffawL + (((size_t)w * 8 + kc) * 64 + l) * 8);
            oacc = __builtin_amdgcn_mfma_f32_16x16x32_bf16(a, b, oacc, 0, 0, 0);
        }
        int gcol = w * 16 + fr;
        float bz = bOAL[gcol];
        #pragma unroll
        for (int r = 0; r < 4; r++)
            Slds[(rb + r) * 204 + gcol] = oacc[r] + bz;
    }
    __syncthreads();

    // ---- phase 2: softmax + bilinear sampling, wave per row ----
    {
        const int h = l >> 3, dg = l & 7;
        const int ch0 = h * 32 + dg * 4;
        int m = m0 + w, q = m & (NQQ - 1), bidx = m >> 12;
        float rxs, rys;
        if (SELF) { rxs = (float)(q & 63) * 64.0f + 32.0f; rys = (float)(q >> 6) * 64.0f + 32.0f; }
        else      { rxs = refp[q * 2] * 64.0f;             rys = refp[q * 2 + 1] * 64.0f; }
        const float* oa = Slds + w * 204;
        float lg[8];
        #pragma unroll
        for (int p = 0; p < 8; p++) lg[p] = oa[128 + h * 8 + p];
        float mx = lg[0];
        #pragma unroll
        for (int p = 1; p < 8; p++) mx = fmaxf(mx, lg[p]);
        float wg[8], wsum = 0.0f;
        #pragma unroll
        for (int p = 0; p < 8; p++) { wg[p] = __expf(lg[p] - mx); wsum += wg[p]; }
        float inv = 1.0f / wsum;
        const float* offp = oa + h * 16;
        const ushort* vb = value + (size_t)bidx * NQQ * vstride + ch0;
        float acc[4] = {};
        #pragma unroll
        for (int p = 0; p < 8; p++) {
            float px = rxs + offp[p * 2]     - 0.5f;
            float py = rys + offp[p * 2 + 1] - 0.5f;
            float x0f = floorf(px), y0f = floorf(py);
            float lx = px - x0f, ly = py - y0f;
            int x0 = (int)x0f, y0 = (int)y0f;
            float wgt = wg[p] * inv;
            float w00 = (1 - lx) * (1 - ly) * wgt, w10 = lx * (1 - ly) * wgt;
            float w01 = (1 - lx) * ly * wgt,       w11 = lx * ly * wgt;
            #pragma unroll
            for (int cn = 0; cn < 4; cn++) {
                int xi = x0 + (cn & 1), yi = y0 + (cn >> 1);
                float wc = (cn == 0) ? w00 : (cn == 1) ? w10 : (cn == 2) ? w01 : w11;
                if (xi >= 0 && xi < 64 && yi >= 0 && yi < 64) {
                    uint2 uv = *(const uint2*)(vb + (size_t)(yi * 64 + xi) * vstride);
                    uint u0 = uv.x, u1 = uv.y;
                    uint a0 = u0 << 16, a1 = u0 & 0xffff0000u;
                    uint a2 = u1 << 16, a3 = u1 & 0xffff0000u;
                    acc[0] += wc * *reinterpret_cast<float*>(&a0);
                    acc[1] += wc * *reinterpret_cast<float*>(&a1);
                    acc[2] += wc * *reinterpret_cast<float*>(&a2);
                    acc[3] += wc * *reinterpret_cast<float*>(&a3);
                }
            }
        }
        ushort4 pk;
        pk.x = f2bu(acc[0]); pk.y = f2bu(acc[1]); pk.z = f2bu(acc[2]); pk.w = f2bu(acc[3]);
        *(ushort4*)(Abuf + w * 264 + ch0) = pk;
    }
    __syncthreads();

    const int gcol = w * 16 + fr;

    // ---- phase 3: out-proj + residual (v in regs) + LN2 stats ----
    float v[4];
    {
        f4v acc = {};
        #pragma unroll
        for (int kc = 0; kc < 8; kc++) {
            s8v a = *(const s8v*)(Abuf + fr * 264 + kc * 32 + fk8);
            s8v b = *(const s8v*)(woutL + (((size_t)w * 8 + kc) * 64 + l) * 8);
            acc = __builtin_amdgcn_mfma_f32_16x16x32_bf16(a, b, acc, 0, 0, 0);
        }
        float ls[4], lq[4];
        float bz = out_bL[gcol];
        #pragma unroll
        for (int r = 0; r < 4; r++) {
            float tv = tgt[(size_t)(m0 + rb + r) * 256 + gcol] + acc[r] + bz;
            v[r] = tv;
            ls[r] = tv;
            lq[r] = tv * tv;
        }
        #pragma unroll
        for (int o = 1; o < 16; o <<= 1)
            #pragma unroll
            for (int r = 0; r < 4; r++) {
                ls[r] += __shfl_xor(ls[r], o);
                lq[r] += __shfl_xor(lq[r], o);
            }
        if (fr == 0)
            #pragma unroll
            for (int r = 0; r < 4; r++) {
                pred[0][w][rb + r] = ls[r];
                pred[1][w][rb + r] = lq[r];
            }
    }
    __syncthreads();

    // ---- LN2 normalize -> Abuf ----
    #pragma unroll
    for (int r = 0; r < 4; r++) {
        int rloc = rb + r;
        float s = 0.0f, sq = 0.0f;
        #pragma unroll
        for (int ww = 0; ww < 16; ww++) { s += pred[0][ww][rloc]; sq += pred[1][ww][rloc]; }
        float mean = s * (1.0f / 256.0f);
        float var = sq * (1.0f / 256.0f) - mean * mean;
        float rstd = rsqrtf(var + 1e-5f);
        Abuf[rloc * 264 + gcol] = f2bu((v[r] - mean) * rstd * g2[gcol] + b2[gcol]);
    }
    __syncthreads();

    // ---- phase 4: FFN1 + relu -> Abuf ----
    {
        f4v acc = {};
        #pragma unroll
        for (int kc = 0; kc < 8; kc++) {
            s8v a = *(const s8v*)(Abuf + fr * 264 + kc * 32 + fk8);
            s8v b = *(const s8v*)(wf1L + (((size_t)w * 8 + kc) * 64 + l) * 8);
            acc = __builtin_amdgcn_mfma_f32_16x16x32_bf16(a, b, acc, 0, 0, 0);
        }
        __syncthreads();
        float bz = f1_bL[gcol];
        #pragma unroll
        for (int r = 0; r < 4; r++)
            Abuf[(rb + r) * 264 + gcol] = f2bu(fmaxf(acc[r] + bz, 0.0f));
    }
    __syncthreads();

    // ---- phase 5: FFN2 + relu + residual, final write (+ stage for value if EMITVAL) ----
    {
        f4v acc = {};
        #pragma unroll
        for (int kc = 0; kc < 8; kc++) {
            s8v a = *(const s8v*)(Abuf + fr * 264 + kc * 32 + fk8);
            s8v b = *(const s8v*)(wf2L + (((size_t)w * 8 + kc) * 64 + l) * 8);
            acc = __builtin_amdgcn_mfma_f32_16x16x32_bf16(a, b, acc, 0, 0, 0);
        }
        if (EMITVAL) __syncthreads();       // drain Abuf reads before overwrite
        float bz = f2_bL[gcol];
        #pragma unroll
        for (int r = 0; r < 4; r++) {
            float fin = v[r] + fmaxf(acc[r] + bz, 0.0f);
            tgt[(size_t)(m0 + rb + r) * 256 + gcol] = fin;
            if (EMITVAL) Abuf[(rb + r) * 264 + gcol] = f2bu(fin);
        }
    }
    if (EMITVAL) {
        __syncthreads();
        // ---- phase 6: value projection for next layer ----
        f4v acc = {};
        #pragma unroll
        for (int kc = 0; kc < 8; kc++) {
            s8v a = *(const s8v*)(Abuf + fr * 264 + kc * 32 + fk8);
            s8v b = *(const s8v*)(wvalN + (((size_t)w * 8 + kc) * 64 + l) * 8);
            acc = __builtin_amdgcn_mfma_f32_16x16x32_bf16(a, b, acc, 0, 0, 0);
        }
        float bz = val_bN[gcol];
        #pragma unroll
        for (int r = 0; r < 4; r++)
            valueOut[(size_t)(m0 + rb + r) * 256 + gcol] = f2bu(acc[r] + bz);
    }
}

extern "C" void kernel_launch(void* const* d_in, const int* in_sizes, int n_in,
                              void* d_out, int out_size, void* d_ws, size_t ws_size,
                              hipStream_t stream) {
    const float* feat0 = (const float*)d_in[0];
    const float* feat1 = (const float*)d_in[1];
    const float* qemb  = (const float*)d_in[2];
    const float* ref_w = (const float*)d_in[3];
    const float* ref_b = (const float*)d_in[4];
    const float* fl    = (const float*)d_in[5];
    const float* ln1_g = (const float*)d_in[6];
    const float* ln1_b = (const float*)d_in[7];
    const float* off_w = (const float*)d_in[8];
    const float* off_b = (const float*)d_in[9];
    const float* aw_w  = (const float*)d_in[10];
    const float* aw_b  = (const float*)d_in[11];
    const float* val_w = (const float*)d_in[12];
    const float* val_b = (const float*)d_in[13];
    const float* out_w = (const float*)d_in[14];
    const float* out_b = (const float*)d_in[15];
    const float* ln2_g = (const float*)d_in[16];
    const float* ln2_b = (const float*)d_in[17];
    const float* f1_w  = (const float*)d_in[18];
    const float* f1_b  = (const float*)d_in[19];
    const float* f2_w  = (const float*)d_in[20];
    const float* f2_b  = (const float*)d_in[21];

    float* tgt = (float*)d_out;
    float* ws = (float*)d_ws;
    float* pos     = ws;                                     // 1,048,576 f32
    float* refp    = pos + 1048576;                          // 8,192 f32
    float* bOA     = refp + 8192;                            // 768 f32
    ushort* value01= (ushort*)(bOA + 768);                   // MT*512
    ushort* valueS0= value01 + (size_t)MT * 512;             // MT*256
    ushort* valueS1= valueS0 + (size_t)MT * 256;             // MT*256
    ushort* wval01 = valueS1 + (size_t)MT * 256;             // 131072
    ushort* wvalS  = wval01 + 131072;                        // 131072
    ushort* woffaw = wvalS + 131072;                         // 196608
    ushort* wout   = woffaw + 196608;                        // 262144
    ushort* wf1    = wout + 262144;                          // 262144
    ushort* wf2    = wf1 + 262144;                           // 262144
    ushort* fused_bf = wf2 + 262144;                         // MT*256

    setup_kernel<<<5940, 256, 0, stream>>>(qemb, ref_w, ref_b, feat0, feat1, fl,
                                           val_w, off_w, aw_w, out_w, f1_w, f2_w,
                                           off_b, aw_b,
                                           pos, refp, tgt,
                                           wval01, wvalS, woffaw, wout, wf1, wf2,
                                           bOA, fused_bf);

    // value projections for both cross layers: [MT,512] bf16
    pgemm<0, 2><<<dim3(512, 2), 512, 0, stream>>>(fused_bf, nullptr, wval01, val_b, value01, 512);

    // L0 (cross)
    layer_kernel<0, 0><<<512, 1024, 0, stream>>>(
        tgt, qemb, ln1_g, ln1_b,
        woffaw, bOA, value01, 512, refp,
        wout, out_b, ln2_g, ln2_b,
        wf1, f1_b, wf2, f2_b,
        nullptr, nullptr, nullptr);
    // L1 (cross, emit value for L2)
    layer_kernel<0, 1><<<512, 1024, 0, stream>>>(
        tgt, qemb, ln1_g + CC, ln1_b + CC,
        woffaw + 49152, bOA + 192, value01 + 256, 512, refp,
        wout + 65536, out_b + CC, ln2_g + CC, ln2_b + CC,
        wf1 + 65536, f1_b + CC, wf2 + 65536, f2_b + CC,
        wvalS, val_b + 2 * CC, valueS0);
    // L2 (self, emit value for L3)
    layer_kernel<1, 1><<<512, 1024, 0, stream>>>(
        tgt, pos, nullptr, nullptr,
        woffaw + 2 * 49152, bOA + 2 * 192, valueS0, 256, refp,
        wout + 2 * 65536, out_b + 2 * CC, ln2_g + 2 * CC, ln2_b + 2 * CC,
        wf1 + 2 * 65536, f1_b + 2 * CC, wf2 + 2 * 65536, f2_b + 2 * CC,
        wvalS + 65536, val_b + 3 * CC, valueS1);
    // L3 (self)
    layer_kernel<1, 0><<<512, 1024, 0, stream>>>(
        tgt, pos, nullptr, nullptr,
        woffaw + 3 * 49152, bOA + 3 * 192, valueS1, 256, refp,
        wout + 3 * 65536, out_b + 3 * CC, ln2_g + 3 * CC, ln2_b + 3 * CC,
        wf1 + 3 * 65536, f1_b + 3 * CC, wf2 + 3 * 65536, f2_b + 3 * CC,
        nullptr, nullptr, nullptr);
}

// Round 9
// 136.961 us; speedup vs baseline: 1.3960x; 1.3960x over previous
//
#include <hip/hip_runtime.h>
#include <hip/hip_bf16.h>
#include <math.h>

#define CC   256
#define NQQ  4096
#define MT   8192

typedef __attribute__((ext_vector_type(8))) short s8v;
typedef __attribute__((ext_vector_type(4))) float f4v;

static __device__ __forceinline__ ushort f2bu(float f) {
    __hip_bfloat16 h = __float2bfloat16(f);
    return *reinterpret_cast<ushort*>(&h);
}

// Fragment layout for weights: Wf[((ntile*8 + kc)*64 + lane)*8 + e]
//   lane l supplies B rows (n = ntile*16 + (l&15)), k = kc*32 + (l>>4)*8 + e
// => a wave's fragment load is 64 lanes x 16B contiguous (1KB), fully coalesced.

// ======== setup: pos/refpts/tgt-init + weight->fragment transpose + fuse ========
__global__ __launch_bounds__(256) void setup_kernel(
        const float* __restrict__ qemb, const float* __restrict__ rw,
        const float* __restrict__ rb,
        const float* __restrict__ feat0, const float* __restrict__ feat1,
        const float* __restrict__ fl,
        const float* __restrict__ val_w, const float* __restrict__ off_w,
        const float* __restrict__ aw_w,  const float* __restrict__ out_w,
        const float* __restrict__ f1_w,  const float* __restrict__ f2_w,
        const float* __restrict__ off_b, const float* __restrict__ aw_b,
        float* __restrict__ pos, float* __restrict__ refp, float* __restrict__ tgt,
        ushort* __restrict__ wval01, ushort* __restrict__ wvalS,
        ushort* __restrict__ woffaw, ushort* __restrict__ wout,
        ushort* __restrict__ wf1, ushort* __restrict__ wf2,
        float* __restrict__ bOA, ushort* __restrict__ fused) {
    __shared__ float tl[64][65];
    int bid = blockIdx.x;
    int t = threadIdx.x;
    if (bid < 2048) {                       // pos
        int idx = bid * 256 + t;
        int q = idx >> 7, pp = idx & 127;
        int p = pp >> 6, u = pp & 63;
        float coordbase = (p == 0) ? (float)((q >> 6) + 1) : (float)((q & 63) + 1);
        float coord = coordbase * (6.28318530717958647692f / (64.0f + 1e-6f));
        float v = coord * exp2f(-0.20762050593046016f * (float)u);
        *(float2*)(pos + (size_t)q * 256 + p * 128 + u * 2) = make_float2(__sinf(v), __cosf(v));
        return;
    }
    if (bid < 3072) {                       // refpts
        int row = (bid - 2048) * 4 + (t >> 6);
        int l = t & 63;
        float4 v = *(const float4*)(qemb + (size_t)row * 512 + l * 4);
        float a0 = v.x * rw[(l * 4 + 0) * 2] + v.y * rw[(l * 4 + 1) * 2]
                 + v.z * rw[(l * 4 + 2) * 2] + v.w * rw[(l * 4 + 3) * 2];
        float a1 = v.x * rw[(l * 4 + 0) * 2 + 1] + v.y * rw[(l * 4 + 1) * 2 + 1]
                 + v.z * rw[(l * 4 + 2) * 2 + 1] + v.w * rw[(l * 4 + 3) * 2 + 1];
        #pragma unroll
        for (int o = 32; o > 0; o >>= 1) { a0 += __shfl_xor(a0, o); a1 += __shfl_xor(a1, o); }
        if (l == 0) {
            refp[row * 2 + 0] = 1.0f / (1.0f + __expf(-(a0 + rb[0])));
            refp[row * 2 + 1] = 1.0f / (1.0f + __expf(-(a1 + rb[1])));
        }
        return;
    }
    if (bid < 5120) {                       // tgt init
        int idx = (bid - 3072) * 256 + t;
        int c4 = idx & 63;
        int q = (idx >> 6) & (NQQ - 1);
        *(float4*)(tgt + (size_t)idx * 4) = *(const float4*)(qemb + (size_t)q * 512 + 256 + c4 * 4);
        return;
    }
    if (bid < 5428) {                       // weight prep -> fragment layout
        int wb = bid - 5120;
        if (wb >= 304) {
            int layer = wb - 304;
            if (t < 192)
                bOA[layer * 192 + t] = (t < 128) ? off_b[layer * 128 + t]
                                                 : aw_b[layer * 64 + (t - 128)];
            return;
        }
        const float* src; ushort* dstF; int srcStride, ntb, kcb;
        if (wb < 32) {
            int nt = wb & 7, kt = wb >> 3;
            int layer = nt >> 2, nn = (nt & 3) * 64;
            src = val_w + (size_t)layer * 65536 + (size_t)kt * 64 * 256 + nn; srcStride = 256;
            dstF = wval01; ntb = nt * 4; kcb = kt * 2;
        } else if (wb < 64) {
            int b = wb - 32; int layer = b >> 4; int kt = (b >> 2) & 3; int nt = b & 3;
            src = val_w + (size_t)(2 + layer) * 65536 + (size_t)kt * 64 * 256 + nt * 64; srcStride = 256;
            dstF = wvalS + (size_t)layer * 65536; ntb = nt * 4; kcb = kt * 2;
        } else if (wb < 112) {
            int b = wb - 64; int layer = b / 12; int rem = b % 12; int kt = rem / 3; int nt = rem % 3;
            if (nt < 2) { src = off_w + (size_t)layer * 256 * 128 + (size_t)kt * 64 * 128 + nt * 64; srcStride = 128; }
            else        { src = aw_w  + (size_t)layer * 256 * 64  + (size_t)kt * 64 * 64;            srcStride = 64;  }
            dstF = woffaw + (size_t)layer * 49152; ntb = nt * 4; kcb = kt * 2;
        } else {
            int b = wb - 112; int fam = b >> 6; int bb = b & 63;
            int layer = bb >> 4; int kt = (bb >> 2) & 3; int nt = bb & 3;
            const float* s0 = (fam == 0) ? out_w : ((fam == 1) ? f1_w : f2_w);
            ushort* d0      = (fam == 0) ? wout  : ((fam == 1) ? wf1  : wf2);
            src = s0 + (size_t)layer * 65536 + (size_t)kt * 64 * 256 + nt * 64; srcStride = 256;
            dstF = d0 + (size_t)layer * 65536; ntb = nt * 4; kcb = kt * 2;
        }
        int r = t >> 6, c = t & 63;
        #pragma unroll
        for (int rr = 0; rr < 64; rr += 4)                 // tl[k_local][n_local]
            tl[rr + r][c] = src[(size_t)(rr + r) * srcStride + c];
        __syncthreads();
        int l = t >> 2;               // 0..63 (lane of fragment)
        int e0 = (t & 3) * 2;         // 0,2,4,6
        int frow = l & 15;            // n within 16-tile
        int fcol = (l >> 4) * 8;      // k offset within chunk
        #pragma unroll
        for (int s = 0; s < 8; s++) {
            int ntl = s & 3, kcl = s >> 2;
            int ntile = ntb + ntl, kc = kcb + kcl;
            ushort2 val;
            val.x = f2bu(tl[kcl * 32 + fcol + e0    ][ntl * 16 + frow]);
            val.y = f2bu(tl[kcl * 32 + fcol + e0 + 1][ntl * 16 + frow]);
            *(ushort2*)(dstF + (((size_t)ntile * 8 + kc) * 64 + l) * 8 + e0) = val;
        }
        return;
    }
    {                                       // fuse
        int fb = bid - 5428;
        int b = fb >> 8;
        int c0 = ((fb >> 6) & 3) * 64;
        int q0 = (fb & 63) * 64;
        int r = t >> 6, c = t & 63;
        #pragma unroll
        for (int rr = 0; rr < 64; rr += 4) {
            int ch = c0 + rr + r;
            float l0 = fl[ch], l1 = fl[CC + ch];
            float m = fmaxf(l0, l1);
            float e0 = __expf(l0 - m), e1 = __expf(l1 - m);
            float inv = 1.0f / (e0 + e1);
            size_t o = ((size_t)b * CC + ch) * NQQ + q0 + c;
            tl[rr + r][c] = (feat0[o] * e0 + feat1[o] * e1) * inv;
        }
        __syncthreads();
        #pragma unroll
        for (int rr = 0; rr < 64; rr += 4)
            fused[((size_t)(b * NQQ + q0 + rr + r)) * CC + c0 + c] = f2bu(tl[c][rr + r]);
    }
}

// ======== projection GEMM: 16-row tiles, 512 threads, fragment-B ========
template<int ASRC, int NTJ>
__global__ __launch_bounds__(512) void pgemm(const ushort* __restrict__ Abf,
        const float* __restrict__ Af, const ushort* __restrict__ Wf,
        const float* __restrict__ bias, ushort* __restrict__ Cb, int NS) {
    __shared__ ushort Abuf[16 * 264];
    const int t = threadIdx.x;
    const int m0 = blockIdx.x * 16;
    const int cb0 = blockIdx.y * 256;
    const int ntb = blockIdx.y * 16;
    {
        const int rg = t >> 5, c0 = (t & 31) * 8;
        ushort* dst = Abuf + rg * 264 + c0;
        if (ASRC == 0) {
            *(int4*)dst = *(const int4*)(Abf + (size_t)(m0 + rg) * 256 + c0);
        } else {
            const float* src = Af + (size_t)(m0 + rg) * 256 + c0;
            ushort tmp[8];
            #pragma unroll
            for (int j = 0; j < 2; j++) {
                float4 v = *(const float4*)(src + j * 4);
                tmp[j * 4 + 0] = f2bu(v.x); tmp[j * 4 + 1] = f2bu(v.y);
                tmp[j * 4 + 2] = f2bu(v.z); tmp[j * 4 + 3] = f2bu(v.w);
            }
            *(int4*)dst = *(const int4*)tmp;
        }
    }
    __syncthreads();
    const int l = t & 63, w = t >> 6;
    const int fr = l & 15, fk8 = (l >> 4) * 8, rb = (l >> 4) * 4;
    f4v acc[NTJ] = {};
    #pragma unroll
    for (int kc = 0; kc < 8; kc++) {
        s8v a = *(const s8v*)(Abuf + fr * 264 + kc * 32 + fk8);
        #pragma unroll
        for (int j = 0; j < NTJ; j++) {
            int nt = ntb + j * 8 + w;
            s8v b = *(const s8v*)(Wf + (((size_t)nt * 8 + kc) * 64 + l) * 8);
            acc[j] = __builtin_amdgcn_mfma_f32_16x16x32_bf16(a, b, acc[j], 0, 0, 0);
        }
    }
    #pragma unroll
    for (int j = 0; j < NTJ; j++) {
        int gcol = cb0 + (j * 8 + w) * 16 + fr;
        float bz = bias[gcol];
        #pragma unroll
        for (int r = 0; r < 4; r++)
            Cb[(size_t)(m0 + rb + r) * NS + gcol] = f2bu(acc[j][r] + bz);
    }
}

// ======== full decoder layer: 16 rows/block, 512 threads (8 waves) ========
// SELF: query source. EMITVAL: append next layer's value projection from final tgt.
template<int SELF, int EMITVAL>
__global__ __launch_bounds__(512) void layer_kernel(
        float* __restrict__ tgt, const float* __restrict__ posq,
        const float* __restrict__ g1, const float* __restrict__ b1,
        const ushort* __restrict__ woffawL, const float* __restrict__ bOAL,
        const ushort* __restrict__ value, int vstride,
        const float* __restrict__ refp,
        const ushort* __restrict__ woutL, const float* __restrict__ out_bL,
        const float* __restrict__ g2, const float* __restrict__ b2,
        const ushort* __restrict__ wf1L, const float* __restrict__ f1_bL,
        const ushort* __restrict__ wf2L, const float* __restrict__ f2_bL,
        const ushort* __restrict__ wvalN, const float* __restrict__ val_bN,
        ushort* __restrict__ valueOut) {
    __shared__ ushort Abuf[16 * 264];
    __shared__ float Slds[16 * 204];
    __shared__ float pred[2][8][16];
    const int t = threadIdx.x;
    const int m0 = blockIdx.x * 16;

    // ---- phase 0: stage query tile (LN1+qemb | +pos), 8 cols/thread ----
    {
        const int rg = t >> 5, c0 = (t & 31) * 8;
        int m = m0 + rg, q = m & (NQQ - 1);
        const float* src = tgt + (size_t)m * 256 + c0;
        float fv[8];
        *(float4*)&fv[0] = *(const float4*)src;
        *(float4*)&fv[4] = *(const float4*)(src + 4);
        if (!SELF) {
            float s = 0.0f;
            #pragma unroll
            for (int k = 0; k < 8; k++) s += fv[k];
            s += __shfl_xor(s, 1); s += __shfl_xor(s, 2); s += __shfl_xor(s, 4);
            s += __shfl_xor(s, 8); s += __shfl_xor(s, 16);
            float mean = s * (1.0f / 256.0f);
            float s2 = 0.0f;
            #pragma unroll
            for (int k = 0; k < 8; k++) { float d = fv[k] - mean; s2 += d * d; }
            s2 += __shfl_xor(s2, 1); s2 += __shfl_xor(s2, 2); s2 += __shfl_xor(s2, 4);
            s2 += __shfl_xor(s2, 8); s2 += __shfl_xor(s2, 16);
            float rstd = rsqrtf(s2 * (1.0f / 256.0f) + 1e-5f);
            const float* ep = posq + (size_t)q * 512 + c0;     // qemb[:, :C]
            #pragma unroll
            for (int k = 0; k < 8; k++)
                fv[k] = (fv[k] - mean) * rstd * g1[c0 + k] + b1[c0 + k] + ep[k];
        } else {
            const float* ep = posq + (size_t)q * 256 + c0;
            #pragma unroll
            for (int k = 0; k < 8; k++) fv[k] += ep[k];
        }
        ushort tmp[8];
        #pragma unroll
        for (int k = 0; k < 8; k++) tmp[k] = f2bu(fv[k]);
        *(int4*)(Abuf + rg * 264 + c0) = *(const int4*)tmp;
    }
    __syncthreads();

    const int l = t & 63, w = t >> 6;
    const int fr = l & 15, fk8 = (l >> 4) * 8, rb = (l >> 4) * 4;

    // ---- phase 1: offaw GEMM (12 n-tiles over 8 waves) ----
    {
        f4v oacc[2] = {};
        #pragma unroll
        for (int kc = 0; kc < 8; kc++) {
            s8v a = *(const s8v*)(Abuf + fr * 264 + kc * 32 + fk8);
            #pragma unroll
            for (int j = 0; j < 2; j++) {
                int nt = j * 8 + w;
                if (nt < 12) {
                    s8v b = *(const s8v*)(woffawL + (((size_t)nt * 8 + kc) * 64 + l) * 8);
                    oacc[j] = __builtin_amdgcn_mfma_f32_16x16x32_bf16(a, b, oacc[j], 0, 0, 0);
                }
            }
        }
        #pragma unroll
        for (int j = 0; j < 2; j++) {
            int nt = j * 8 + w;
            if (nt < 12) {
                int gcol = nt * 16 + fr;
                float bz = bOAL[gcol];
                #pragma unroll
                for (int r = 0; r < 4; r++)
                    Slds[(rb + r) * 204 + gcol] = oacc[j][r] + bz;
            }
        }
    }
    __syncthreads();

    // ---- phase 2: softmax + bilinear sampling -> Abuf (row, h, 8ch per thread) ----
    {
        const int row = t >> 5, h = (t >> 2) & 7, d8 = t & 3;
        int m = m0 + row, q = m & (NQQ - 1), bidx = m >> 12;
        float rxs, rys;
        if (SELF) { rxs = (float)(q & 63) * 64.0f + 32.0f; rys = (float)(q >> 6) * 64.0f + 32.0f; }
        else      { rxs = refp[q * 2] * 64.0f;             rys = refp[q * 2 + 1] * 64.0f; }
        const float* oa = Slds + row * 204;
        float lg[8];
        #pragma unroll
        for (int p = 0; p < 8; p++) lg[p] = oa[128 + h * 8 + p];
        float mx = lg[0];
        #pragma unroll
        for (int p = 1; p < 8; p++) mx = fmaxf(mx, lg[p]);
        float wg[8], wsum = 0.0f;
        #pragma unroll
        for (int p = 0; p < 8; p++) { wg[p] = __expf(lg[p] - mx); wsum += wg[p]; }
        float inv = 1.0f / wsum;
        const float* offp = oa + h * 16;
        const ushort* vb = value + (size_t)bidx * NQQ * vstride + h * 32 + d8 * 8;
        float acc[8] = {};
        #pragma unroll
        for (int p = 0; p < 8; p++) {
            float px = rxs + offp[p * 2]     - 0.5f;
            float py = rys + offp[p * 2 + 1] - 0.5f;
            float x0f = floorf(px), y0f = floorf(py);
            float lx = px - x0f, ly = py - y0f;
            int x0 = (int)x0f, y0 = (int)y0f;
            float wgt = wg[p] * inv;
            float w00 = (1 - lx) * (1 - ly) * wgt, w10 = lx * (1 - ly) * wgt;
            float w01 = (1 - lx) * ly * wgt,       w11 = lx * ly * wgt;
            #pragma unroll
            for (int cn = 0; cn < 4; cn++) {
                int xi = x0 + (cn & 1), yi = y0 + (cn >> 1);
                float wc = (cn == 0) ? w00 : (cn == 1) ? w10 : (cn == 2) ? w01 : w11;
                if (xi >= 0 && xi < 64 && yi >= 0 && yi < 64) {
                    uint4 uv = *(const uint4*)(vb + (size_t)(yi * 64 + xi) * vstride);
                    uint ua[4] = {uv.x, uv.y, uv.z, uv.w};
                    #pragma unroll
                    for (int k = 0; k < 4; k++) {
                        uint lo = ua[k] << 16;
                        uint hi = ua[k] & 0xffff0000u;
                        acc[k * 2 + 0] += wc * *reinterpret_cast<float*>(&lo);
                        acc[k * 2 + 1] += wc * *reinterpret_cast<float*>(&hi);
                    }
                }
            }
        }
        ushort pk[8];
        #pragma unroll
        for (int k = 0; k < 8; k++) pk[k] = f2bu(acc[k]);
        *(int4*)(Abuf + row * 264 + h * 32 + d8 * 8) = *(const int4*)pk;
    }
    __syncthreads();

    // ---- phase 3: out-proj + residual (v in regs) + LN2 stats ----
    float v[4][2];
    {
        f4v acc[2] = {};
        #pragma unroll
        for (int kc = 0; kc < 8; kc++) {
            s8v a = *(const s8v*)(Abuf + fr * 264 + kc * 32 + fk8);
            #pragma unroll
            for (int j = 0; j < 2; j++) {
                int nt = j * 8 + w;
                s8v b = *(const s8v*)(woutL + (((size_t)nt * 8 + kc) * 64 + l) * 8);
                acc[j] = __builtin_amdgcn_mfma_f32_16x16x32_bf16(a, b, acc[j], 0, 0, 0);
            }
        }
        float ls[4] = {}, lq[4] = {};
        #pragma unroll
        for (int j = 0; j < 2; j++) {
            int gcol = (j * 8 + w) * 16 + fr;
            float bz = out_bL[gcol];
            #pragma unroll
            for (int r = 0; r < 4; r++) {
                float tv = tgt[(size_t)(m0 + rb + r) * 256 + gcol] + acc[j][r] + bz;
                v[r][j] = tv;
                ls[r] += tv;
                lq[r] += tv * tv;
            }
        }
        #pragma unroll
        for (int o = 1; o < 16; o <<= 1)
            #pragma unroll
            for (int r = 0; r < 4; r++) {
                ls[r] += __shfl_xor(ls[r], o);
                lq[r] += __shfl_xor(lq[r], o);
            }
        if (fr == 0)
            #pragma unroll
            for (int r = 0; r < 4; r++) {
                pred[0][w][rb + r] = ls[r];
                pred[1][w][rb + r] = lq[r];
            }
    }
    __syncthreads();

    // ---- LN2 normalize -> Abuf ----
    #pragma unroll
    for (int r = 0; r < 4; r++) {
        int rloc = rb + r;
        float s = 0.0f, sq = 0.0f;
        #pragma unroll
        for (int ww = 0; ww < 8; ww++) { s += pred[0][ww][rloc]; sq += pred[1][ww][rloc]; }
        float mean = s * (1.0f / 256.0f);
        float var = sq * (1.0f / 256.0f) - mean * mean;
        float rstd = rsqrtf(var + 1e-5f);
        #pragma unroll
        for (int j = 0; j < 2; j++) {
            int gcol = (j * 8 + w) * 16 + fr;
            Abuf[rloc * 264 + gcol] = f2bu((v[r][j] - mean) * rstd * g2[gcol] + b2[gcol]);
        }
    }
    __syncthreads();

    // ---- phase 4: FFN1 + relu -> Abuf ----
    {
        f4v acc[2] = {};
        #pragma unroll
        for (int kc = 0; kc < 8; kc++) {
            s8v a = *(const s8v*)(Abuf + fr * 264 + kc * 32 + fk8);
            #pragma unroll
            for (int j = 0; j < 2; j++) {
                int nt = j * 8 + w;
                s8v b = *(const s8v*)(wf1L + (((size_t)nt * 8 + kc) * 64 + l) * 8);
                acc[j] = __builtin_amdgcn_mfma_f32_16x16x32_bf16(a, b, acc[j], 0, 0, 0);
            }
        }
        __syncthreads();
        #pragma unroll
        for (int j = 0; j < 2; j++) {
            int gcol = (j * 8 + w) * 16 + fr;
            float bz = f1_bL[gcol];
            #pragma unroll
            for (int r = 0; r < 4; r++)
                Abuf[(rb + r) * 264 + gcol] = f2bu(fmaxf(acc[j][r] + bz, 0.0f));
        }
    }
    __syncthreads();

    // ---- phase 5: FFN2 + relu + residual, final write (+ restage if EMITVAL) ----
    {
        f4v acc[2] = {};
        #pragma unroll
        for (int kc = 0; kc < 8; kc++) {
            s8v a = *(const s8v*)(Abuf + fr * 264 + kc * 32 + fk8);
            #pragma unroll
            for (int j = 0; j < 2; j++) {
                int nt = j * 8 + w;
                s8v b = *(const s8v*)(wf2L + (((size_t)nt * 8 + kc) * 64 + l) * 8);
                acc[j] = __builtin_amdgcn_mfma_f32_16x16x32_bf16(a, b, acc[j], 0, 0, 0);
            }
        }
        if (EMITVAL) __syncthreads();       // drain Abuf reads before overwrite
        #pragma unroll
        for (int j = 0; j < 2; j++) {
            int gcol = (j * 8 + w) * 16 + fr;
            float bz = f2_bL[gcol];
            #pragma unroll
            for (int r = 0; r < 4; r++) {
                float fin = v[r][j] + fmaxf(acc[j][r] + bz, 0.0f);
                tgt[(size_t)(m0 + rb + r) * 256 + gcol] = fin;
                if (EMITVAL) Abuf[(rb + r) * 264 + gcol] = f2bu(fin);
            }
        }
    }
    if (EMITVAL) {
        __syncthreads();
        // ---- phase 6: next layer's value projection from in-LDS tgt ----
        f4v acc[2] = {};
        #pragma unroll
        for (int kc = 0; kc < 8; kc++) {
            s8v a = *(const s8v*)(Abuf + fr * 264 + kc * 32 + fk8);
            #pragma unroll
            for (int j = 0; j < 2; j++) {
                int nt = j * 8 + w;
                s8v b = *(const s8v*)(wvalN + (((size_t)nt * 8 + kc) * 64 + l) * 8);
                acc[j] = __builtin_amdgcn_mfma_f32_16x16x32_bf16(a, b, acc[j], 0, 0, 0);
            }
        }
        #pragma unroll
        for (int j = 0; j < 2; j++) {
            int gcol = (j * 8 + w) * 16 + fr;
            float bz = val_bN[gcol];
            #pragma unroll
            for (int r = 0; r < 4; r++)
                valueOut[(size_t)(m0 + rb + r) * 256 + gcol] = f2bu(acc[j][r] + bz);
        }
    }
}

extern "C" void kernel_launch(void* const* d_in, const int* in_sizes, int n_in,
                              void* d_out, int out_size, void* d_ws, size_t ws_size,
                              hipStream_t stream) {
    const float* feat0 = (const float*)d_in[0];
    const float* feat1 = (const float*)d_in[1];
    const float* qemb  = (const float*)d_in[2];
    const float* ref_w = (const float*)d_in[3];
    const float* ref_b = (const float*)d_in[4];
    const float* fl    = (const float*)d_in[5];
    const float* ln1_g = (const float*)d_in[6];
    const float* ln1_b = (const float*)d_in[7];
    const float* off_w = (const float*)d_in[8];
    const float* off_b = (const float*)d_in[9];
    const float* aw_w  = (const float*)d_in[10];
    const float* aw_b  = (const float*)d_in[11];
    const float* val_w = (const float*)d_in[12];
    const float* val_b = (const float*)d_in[13];
    const float* out_w = (const float*)d_in[14];
    const float* out_b = (const float*)d_in[15];
    const float* ln2_g = (const float*)d_in[16];
    const float* ln2_b = (const float*)d_in[17];
    const float* f1_w  = (const float*)d_in[18];
    const float* f1_b  = (const float*)d_in[19];
    const float* f2_w  = (const float*)d_in[20];
    const float* f2_b  = (const float*)d_in[21];

    float* tgt = (float*)d_out;
    float* ws = (float*)d_ws;
    float* pos     = ws;                                     // 1,048,576 f32
    float* refp    = pos + 1048576;                          // 8,192 f32
    float* bOA     = refp + 8192;                            // 768 f32
    ushort* value01= (ushort*)(bOA + 768);                   // MT*512
    ushort* valueS0= value01 + (size_t)MT * 512;             // MT*256
    ushort* valueS1= valueS0 + (size_t)MT * 256;             // MT*256
    ushort* wval01 = valueS1 + (size_t)MT * 256;             // 131072
    ushort* wvalS  = wval01 + 131072;                        // 131072
    ushort* woffaw = wvalS + 131072;                         // 196608
    ushort* wout   = woffaw + 196608;                        // 262144
    ushort* wf1    = wout + 262144;                          // 262144
    ushort* wf2    = wf1 + 262144;                           // 262144
    ushort* fused_bf = wf2 + 262144;                         // MT*256

    setup_kernel<<<5940, 256, 0, stream>>>(qemb, ref_w, ref_b, feat0, feat1, fl,
                                           val_w, off_w, aw_w, out_w, f1_w, f2_w,
                                           off_b, aw_b,
                                           pos, refp, tgt,
                                           wval01, wvalS, woffaw, wout, wf1, wf2,
                                           bOA, fused_bf);

    // value projections for both cross layers: [MT,512] bf16
    pgemm<0, 2><<<dim3(512, 2), 512, 0, stream>>>(fused_bf, nullptr, wval01, val_b, value01, 512);

    // L0 (cross)
    layer_kernel<0, 0><<<512, 512, 0, stream>>>(
        tgt, qemb, ln1_g, ln1_b,
        woffaw, bOA, value01, 512, refp,
        wout, out_b, ln2_g, ln2_b,
        wf1, f1_b, wf2, f2_b,
        nullptr, nullptr, nullptr);
    // L1 (cross, emit value for L2)
    layer_kernel<0, 1><<<512, 512, 0, stream>>>(
        tgt, qemb, ln1_g + CC, ln1_b + CC,
        woffaw + 49152, bOA + 192, value01 + 256, 512, refp,
        wout + 65536, out_b + CC, ln2_g + CC, ln2_b + CC,
        wf1 + 65536, f1_b + CC, wf2 + 65536, f2_b + CC,
        wvalS, val_b + 2 * CC, valueS0);
    // L2 (self, emit value for L3)
    layer_kernel<1, 1><<<512, 512, 0, stream>>>(
        tgt, pos, nullptr, nullptr,
        woffaw + 2 * 49152, bOA + 2 * 192, valueS0, 256, refp,
        wout + 2 * 65536, out_b + 2 * CC, ln2_g + 2 * CC, ln2_b + 2 * CC,
        wf1 + 2 * 65536, f1_b + 2 * CC, wf2 + 2 * 65536, f2_b + 2 * CC,
        wvalS + 65536, val_b + 3 * CC, valueS1);
    // L3 (self)
    layer_kernel<1, 0><<<512, 512, 0, stream>>>(
        tgt, pos, nullptr, nullptr,
        woffaw + 3 * 49152, bOA + 3 * 192, valueS1, 256, refp,
        wout + 3 * 65536, out_b + 3 * CC, ln2_g + 3 * CC, ln2_b + 3 * CC,
        wf1 + 3 * 65536, f1_b + 3 * CC, wf2 + 3 * 65536, f2_b + 3 * CC,
        nullptr, nullptr, nullptr);
}

// Round 10
// 115.911 us; speedup vs baseline: 1.6495x; 1.1816x over previous
//
#include <hip/hip_runtime.h>
#include <hip/hip_bf16.h>
#include <math.h>

#define CC   256
#define NQQ  4096
#define MT   8192

typedef __attribute__((ext_vector_type(8))) short s8v;
typedef __attribute__((ext_vector_type(4))) float f4v;

static __device__ __forceinline__ ushort f2bu(float f) {
    __hip_bfloat16 h = __float2bfloat16(f);
    return *reinterpret_cast<ushort*>(&h);
}

// Fragment layout for weights: Wf[((ntile*8 + kc)*64 + lane)*8 + e]
//   lane l supplies B rows (n = ntile*16 + (l&15)), k = kc*32 + (l>>4)*8 + e

// ======== setup: pos/refpts/tgt-init + weight->fragment transpose + fuse ========
__global__ __launch_bounds__(256) void setup_kernel(
        const float* __restrict__ qemb, const float* __restrict__ rw,
        const float* __restrict__ rb,
        const float* __restrict__ feat0, const float* __restrict__ feat1,
        const float* __restrict__ fl,
        const float* __restrict__ val_w, const float* __restrict__ off_w,
        const float* __restrict__ aw_w,  const float* __restrict__ out_w,
        const float* __restrict__ f1_w,  const float* __restrict__ f2_w,
        const float* __restrict__ off_b, const float* __restrict__ aw_b,
        float* __restrict__ pos, float* __restrict__ refp, float* __restrict__ tgt,
        ushort* __restrict__ wval01, ushort* __restrict__ wvalS,
        ushort* __restrict__ woffaw, ushort* __restrict__ wout,
        ushort* __restrict__ wf1, ushort* __restrict__ wf2,
        float* __restrict__ bOA, ushort* __restrict__ fused) {
    __shared__ float tl[64][65];
    int bid = blockIdx.x;
    int t = threadIdx.x;
    if (bid < 2048) {                       // pos
        int idx = bid * 256 + t;
        int q = idx >> 7, pp = idx & 127;
        int p = pp >> 6, u = pp & 63;
        float coordbase = (p == 0) ? (float)((q >> 6) + 1) : (float)((q & 63) + 1);
        float coord = coordbase * (6.28318530717958647692f / (64.0f + 1e-6f));
        float v = coord * exp2f(-0.20762050593046016f * (float)u);
        *(float2*)(pos + (size_t)q * 256 + p * 128 + u * 2) = make_float2(__sinf(v), __cosf(v));
        return;
    }
    if (bid < 3072) {                       // refpts
        int row = (bid - 2048) * 4 + (t >> 6);
        int l = t & 63;
        float4 v = *(const float4*)(qemb + (size_t)row * 512 + l * 4);
        float a0 = v.x * rw[(l * 4 + 0) * 2] + v.y * rw[(l * 4 + 1) * 2]
                 + v.z * rw[(l * 4 + 2) * 2] + v.w * rw[(l * 4 + 3) * 2];
        float a1 = v.x * rw[(l * 4 + 0) * 2 + 1] + v.y * rw[(l * 4 + 1) * 2 + 1]
                 + v.z * rw[(l * 4 + 2) * 2 + 1] + v.w * rw[(l * 4 + 3) * 2 + 1];
        #pragma unroll
        for (int o = 32; o > 0; o >>= 1) { a0 += __shfl_xor(a0, o); a1 += __shfl_xor(a1, o); }
        if (l == 0) {
            refp[row * 2 + 0] = 1.0f / (1.0f + __expf(-(a0 + rb[0])));
            refp[row * 2 + 1] = 1.0f / (1.0f + __expf(-(a1 + rb[1])));
        }
        return;
    }
    if (bid < 5120) {                       // tgt init
        int idx = (bid - 3072) * 256 + t;
        int c4 = idx & 63;
        int q = (idx >> 6) & (NQQ - 1);
        *(float4*)(tgt + (size_t)idx * 4) = *(const float4*)(qemb + (size_t)q * 512 + 256 + c4 * 4);
        return;
    }
    if (bid < 5428) {                       // weight prep -> fragment layout
        int wb = bid - 5120;
        if (wb >= 304) {
            int layer = wb - 304;
            if (t < 192)
                bOA[layer * 192 + t] = (t < 128) ? off_b[layer * 128 + t]
                                                 : aw_b[layer * 64 + (t - 128)];
            return;
        }
        const float* src; ushort* dstF; int srcStride, ntb, kcb;
        if (wb < 32) {
            int nt = wb & 7, kt = wb >> 3;
            int layer = nt >> 2, nn = (nt & 3) * 64;
            src = val_w + (size_t)layer * 65536 + (size_t)kt * 64 * 256 + nn; srcStride = 256;
            dstF = wval01; ntb = nt * 4; kcb = kt * 2;
        } else if (wb < 64) {
            int b = wb - 32; int layer = b >> 4; int kt = (b >> 2) & 3; int nt = b & 3;
            src = val_w + (size_t)(2 + layer) * 65536 + (size_t)kt * 64 * 256 + nt * 64; srcStride = 256;
            dstF = wvalS + (size_t)layer * 65536; ntb = nt * 4; kcb = kt * 2;
        } else if (wb < 112) {
            int b = wb - 64; int layer = b / 12; int rem = b % 12; int kt = rem / 3; int nt = rem % 3;
            if (nt < 2) { src = off_w + (size_t)layer * 256 * 128 + (size_t)kt * 64 * 128 + nt * 64; srcStride = 128; }
            else        { src = aw_w  + (size_t)layer * 256 * 64  + (size_t)kt * 64 * 64;            srcStride = 64;  }
            dstF = woffaw + (size_t)layer * 49152; ntb = nt * 4; kcb = kt * 2;
        } else {
            int b = wb - 112; int fam = b >> 6; int bb = b & 63;
            int layer = bb >> 4; int kt = (bb >> 2) & 3; int nt = bb & 3;
            const float* s0 = (fam == 0) ? out_w : ((fam == 1) ? f1_w : f2_w);
            ushort* d0      = (fam == 0) ? wout  : ((fam == 1) ? wf1  : wf2);
            src = s0 + (size_t)layer * 65536 + (size_t)kt * 64 * 256 + nt * 64; srcStride = 256;
            dstF = d0 + (size_t)layer * 65536; ntb = nt * 4; kcb = kt * 2;
        }
        int r = t >> 6, c = t & 63;
        #pragma unroll
        for (int rr = 0; rr < 64; rr += 4)                 // tl[k_local][n_local]
            tl[rr + r][c] = src[(size_t)(rr + r) * srcStride + c];
        __syncthreads();
        int l = t >> 2;               // 0..63 (lane of fragment)
        int e0 = (t & 3) * 2;         // 0,2,4,6
        int frow = l & 15;            // n within 16-tile
        int fcol = (l >> 4) * 8;      // k offset within chunk
        #pragma unroll
        for (int s = 0; s < 8; s++) {
            int ntl = s & 3, kcl = s >> 2;
            int ntile = ntb + ntl, kc = kcb + kcl;
            ushort2 val;
            val.x = f2bu(tl[kcl * 32 + fcol + e0    ][ntl * 16 + frow]);
            val.y = f2bu(tl[kcl * 32 + fcol + e0 + 1][ntl * 16 + frow]);
            *(ushort2*)(dstF + (((size_t)ntile * 8 + kc) * 64 + l) * 8 + e0) = val;
        }
        return;
    }
    {                                       // fuse
        int fb = bid - 5428;
        int b = fb >> 8;
        int c0 = ((fb >> 6) & 3) * 64;
        int q0 = (fb & 63) * 64;
        int r = t >> 6, c = t & 63;
        #pragma unroll
        for (int rr = 0; rr < 64; rr += 4) {
            int ch = c0 + rr + r;
            float l0 = fl[ch], l1 = fl[CC + ch];
            float m = fmaxf(l0, l1);
            float e0 = __expf(l0 - m), e1 = __expf(l1 - m);
            float inv = 1.0f / (e0 + e1);
            size_t o = ((size_t)b * CC + ch) * NQQ + q0 + c;
            tl[rr + r][c] = (feat0[o] * e0 + feat1[o] * e1) * inv;
        }
        __syncthreads();
        #pragma unroll
        for (int rr = 0; rr < 64; rr += 4)
            fused[((size_t)(b * NQQ + q0 + rr + r)) * CC + c0 + c] = f2bu(tl[c][rr + r]);
    }
}

// ======== projection GEMM: 32-row tiles, 1024 threads, 1 n-tile/wave, 2 row-groups ======
__global__ __launch_bounds__(1024, 4) void pgemm(const ushort* __restrict__ Abf,
        const ushort* __restrict__ Wf, const float* __restrict__ bias,
        ushort* __restrict__ Cb, int NS) {
    __shared__ ushort Abuf[32 * 264];
    const int t = threadIdx.x;
    const int m0 = blockIdx.x * 32;
    const int cb0 = blockIdx.y * 256;
    const int ntb = blockIdx.y * 16;
    {
        const int rg = t >> 5, c0 = (t & 31) * 8;
        *(int4*)(Abuf + rg * 264 + c0) = *(const int4*)(Abf + (size_t)(m0 + rg) * 256 + c0);
    }
    __syncthreads();
    const int l = t & 63, w = t >> 6;
    const int fr = l & 15, fk8 = (l >> 4) * 8, rb = (l >> 4) * 4;
    f4v acc[2] = {};
    #pragma unroll
    for (int kc = 0; kc < 8; kc++) {
        s8v b = *(const s8v*)(Wf + (((size_t)(ntb + w) * 8 + kc) * 64 + l) * 8);
        s8v a0 = *(const s8v*)(Abuf + fr * 264 + kc * 32 + fk8);
        s8v a1 = *(const s8v*)(Abuf + (16 + fr) * 264 + kc * 32 + fk8);
        acc[0] = __builtin_amdgcn_mfma_f32_16x16x32_bf16(a0, b, acc[0], 0, 0, 0);
        acc[1] = __builtin_amdgcn_mfma_f32_16x16x32_bf16(a1, b, acc[1], 0, 0, 0);
    }
    int gcol = cb0 + w * 16 + fr;
    float bz = bias[gcol];
    #pragma unroll
    for (int g = 0; g < 2; g++)
        #pragma unroll
        for (int r = 0; r < 4; r++)
            Cb[(size_t)(m0 + g * 16 + rb + r) * NS + gcol] = f2bu(acc[g][r] + bz);
}

// ======== full decoder layer: 32 rows/block, 1024 threads (16 waves), grid 256 ========
template<int SELF, int EMITVAL>
__global__ __launch_bounds__(1024, 4) void layer_kernel(
        float* __restrict__ tgt, const float* __restrict__ posq,
        const float* __restrict__ g1, const float* __restrict__ b1,
        const ushort* __restrict__ woffawL, const float* __restrict__ bOAL,
        const ushort* __restrict__ value, int vstride,
        const float* __restrict__ refp,
        const ushort* __restrict__ woutL, const float* __restrict__ out_bL,
        const float* __restrict__ g2, const float* __restrict__ b2,
        const ushort* __restrict__ wf1L, const float* __restrict__ f1_bL,
        const ushort* __restrict__ wf2L, const float* __restrict__ f2_bL,
        const ushort* __restrict__ wvalN, const float* __restrict__ val_bN,
        ushort* __restrict__ valueOut) {
    __shared__ ushort Abuf[32 * 264];          // 16.9 KB
    __shared__ float Slds[32 * 204];           // 26.1 KB
    __shared__ float pred[2][16][32];          // 4 KB
    __shared__ float mrs[2][32];
    const int t = threadIdx.x;
    const int m0 = blockIdx.x * 32;

    // ---- phase 0: stage query tile (LN1+qemb | +pos), 8 cols/thread, 32 rows ----
    {
        const int rg = t >> 5, c0 = (t & 31) * 8;
        int m = m0 + rg, q = m & (NQQ - 1);
        const float* src = tgt + (size_t)m * 256 + c0;
        float fv[8];
        *(float4*)&fv[0] = *(const float4*)src;
        *(float4*)&fv[4] = *(const float4*)(src + 4);
        if (!SELF) {
            float s = 0.0f;
            #pragma unroll
            for (int k = 0; k < 8; k++) s += fv[k];
            s += __shfl_xor(s, 1); s += __shfl_xor(s, 2); s += __shfl_xor(s, 4);
            s += __shfl_xor(s, 8); s += __shfl_xor(s, 16);
            float mean = s * (1.0f / 256.0f);
            float s2 = 0.0f;
            #pragma unroll
            for (int k = 0; k < 8; k++) { float d = fv[k] - mean; s2 += d * d; }
            s2 += __shfl_xor(s2, 1); s2 += __shfl_xor(s2, 2); s2 += __shfl_xor(s2, 4);
            s2 += __shfl_xor(s2, 8); s2 += __shfl_xor(s2, 16);
            float rstd = rsqrtf(s2 * (1.0f / 256.0f) + 1e-5f);
            const float* ep = posq + (size_t)q * 512 + c0;     // qemb[:, :C]
            #pragma unroll
            for (int k = 0; k < 8; k++)
                fv[k] = (fv[k] - mean) * rstd * g1[c0 + k] + b1[c0 + k] + ep[k];
        } else {
            const float* ep = posq + (size_t)q * 256 + c0;
            #pragma unroll
            for (int k = 0; k < 8; k++) fv[k] += ep[k];
        }
        ushort tmp[8];
        #pragma unroll
        for (int k = 0; k < 8; k++) tmp[k] = f2bu(fv[k]);
        *(int4*)(Abuf + rg * 264 + c0) = *(const int4*)tmp;
    }
    __syncthreads();

    const int l = t & 63, w = t >> 6;          // w = 0..15
    const int fr = l & 15, fk8 = (l >> 4) * 8, rb = (l >> 4) * 4;

    // ---- phase 1: offaw GEMM (12 n-tiles, waves 0..11, 2 row-groups each) ----
    if (w < 12) {
        f4v oacc[2] = {};
        #pragma unroll
        for (int kc = 0; kc < 8; kc++) {
            s8v b = *(const s8v*)(woffawL + (((size_t)w * 8 + kc) * 64 + l) * 8);
            s8v a0 = *(const s8v*)(Abuf + fr * 264 + kc * 32 + fk8);
            s8v a1 = *(const s8v*)(Abuf + (16 + fr) * 264 + kc * 32 + fk8);
            oacc[0] = __builtin_amdgcn_mfma_f32_16x16x32_bf16(a0, b, oacc[0], 0, 0, 0);
            oacc[1] = __builtin_amdgcn_mfma_f32_16x16x32_bf16(a1, b, oacc[1], 0, 0, 0);
        }
        int gcol = w * 16 + fr;
        float bz = bOAL[gcol];
        #pragma unroll
        for (int g = 0; g < 2; g++)
            #pragma unroll
            for (int r = 0; r < 4; r++)
                Slds[(g * 16 + rb + r) * 204 + gcol] = oacc[g][r] + bz;
    }
    __syncthreads();

    // ---- phase 2: softmax + bilinear sampling (row = t>>5, h, d8) ----
    {
        const int row = t >> 5, h = (t >> 2) & 7, d8 = t & 3;
        int m = m0 + row, q = m & (NQQ - 1), bidx = m >> 12;
        float rxs, rys;
        if (SELF) { rxs = (float)(q & 63) * 64.0f + 32.0f; rys = (float)(q >> 6) * 64.0f + 32.0f; }
        else      { rxs = refp[q * 2] * 64.0f;             rys = refp[q * 2 + 1] * 64.0f; }
        const float* oa = Slds + row * 204;
        float lg[8];
        #pragma unroll
        for (int p = 0; p < 8; p++) lg[p] = oa[128 + h * 8 + p];
        float mx = lg[0];
        #pragma unroll
        for (int p = 1; p < 8; p++) mx = fmaxf(mx, lg[p]);
        float wg[8], wsum = 0.0f;
        #pragma unroll
        for (int p = 0; p < 8; p++) { wg[p] = __expf(lg[p] - mx); wsum += wg[p]; }
        float inv = 1.0f / wsum;
        const float* offp = oa + h * 16;
        const ushort* vb = value + (size_t)bidx * NQQ * vstride + h * 32 + d8 * 8;
        float acc[8] = {};
        #pragma unroll
        for (int p = 0; p < 8; p++) {
            float px = rxs + offp[p * 2]     - 0.5f;
            float py = rys + offp[p * 2 + 1] - 0.5f;
            float x0f = floorf(px), y0f = floorf(py);
            float lx = px - x0f, ly = py - y0f;
            int x0 = (int)x0f, y0 = (int)y0f;
            float wgt = wg[p] * inv;
            float w00 = (1 - lx) * (1 - ly) * wgt, w10 = lx * (1 - ly) * wgt;
            float w01 = (1 - lx) * ly * wgt,       w11 = lx * ly * wgt;
            #pragma unroll
            for (int cn = 0; cn < 4; cn++) {
                int xi = x0 + (cn & 1), yi = y0 + (cn >> 1);
                float wc = (cn == 0) ? w00 : (cn == 1) ? w10 : (cn == 2) ? w01 : w11;
                if (xi >= 0 && xi < 64 && yi >= 0 && yi < 64) {
                    uint4 uv = *(const uint4*)(vb + (size_t)(yi * 64 + xi) * vstride);
                    uint ua[4] = {uv.x, uv.y, uv.z, uv.w};
                    #pragma unroll
                    for (int k = 0; k < 4; k++) {
                        uint lo = ua[k] << 16;
                        uint hi = ua[k] & 0xffff0000u;
                        acc[k * 2 + 0] += wc * *reinterpret_cast<float*>(&lo);
                        acc[k * 2 + 1] += wc * *reinterpret_cast<float*>(&hi);
                    }
                }
            }
        }
        ushort pk[8];
        #pragma unroll
        for (int k = 0; k < 8; k++) pk[k] = f2bu(acc[k]);
        *(int4*)(Abuf + row * 264 + h * 32 + d8 * 8) = *(const int4*)pk;
    }
    __syncthreads();

    const int gcol = w * 16 + fr;

    // ---- phase 3: out-proj + residual (v in regs) + LN2 stats ----
    float v[2][4];
    {
        f4v acc[2] = {};
        #pragma unroll
        for (int kc = 0; kc < 8; kc++) {
            s8v b = *(const s8v*)(woutL + (((size_t)w * 8 + kc) * 64 + l) * 8);
            s8v a0 = *(const s8v*)(Abuf + fr * 264 + kc * 32 + fk8);
            s8v a1 = *(const s8v*)(Abuf + (16 + fr) * 264 + kc * 32 + fk8);
            acc[0] = __builtin_amdgcn_mfma_f32_16x16x32_bf16(a0, b, acc[0], 0, 0, 0);
            acc[1] = __builtin_amdgcn_mfma_f32_16x16x32_bf16(a1, b, acc[1], 0, 0, 0);
        }
        float ls[2][4], lq[2][4];
        float bz = out_bL[gcol];
        #pragma unroll
        for (int g = 0; g < 2; g++)
            #pragma unroll
            for (int r = 0; r < 4; r++) {
                float tv = tgt[(size_t)(m0 + g * 16 + rb + r) * 256 + gcol] + acc[g][r] + bz;
                v[g][r] = tv;
                ls[g][r] = tv;
                lq[g][r] = tv * tv;
            }
        #pragma unroll
        for (int o = 1; o < 16; o <<= 1)
            #pragma unroll
            for (int g = 0; g < 2; g++)
                #pragma unroll
                for (int r = 0; r < 4; r++) {
                    ls[g][r] += __shfl_xor(ls[g][r], o);
                    lq[g][r] += __shfl_xor(lq[g][r], o);
                }
        if (fr == 0)
            #pragma unroll
            for (int g = 0; g < 2; g++)
                #pragma unroll
                for (int r = 0; r < 4; r++) {
                    pred[0][w][g * 16 + rb + r] = ls[g][r];
                    pred[1][w][g * 16 + rb + r] = lq[g][r];
                }
    }
    __syncthreads();
    if (t < 32) {
        float s = 0.0f, sq = 0.0f;
        #pragma unroll
        for (int ww = 0; ww < 16; ww++) { s += pred[0][ww][t]; sq += pred[1][ww][t]; }
        float mean = s * (1.0f / 256.0f);
        float var = sq * (1.0f / 256.0f) - mean * mean;
        mrs[0][t] = mean;
        mrs[1][t] = rsqrtf(var + 1e-5f);
    }
    __syncthreads();

    // ---- LN2 normalize -> Abuf ----
    #pragma unroll
    for (int g = 0; g < 2; g++)
        #pragma unroll
        for (int r = 0; r < 4; r++) {
            int rloc = g * 16 + rb + r;
            Abuf[rloc * 264 + gcol] = f2bu((v[g][r] - mrs[0][rloc]) * mrs[1][rloc] * g2[gcol] + b2[gcol]);
        }
    __syncthreads();

    // ---- phase 4: FFN1 + relu -> Abuf ----
    {
        f4v acc[2] = {};
        #pragma unroll
        for (int kc = 0; kc < 8; kc++) {
            s8v b = *(const s8v*)(wf1L + (((size_t)w * 8 + kc) * 64 + l) * 8);
            s8v a0 = *(const s8v*)(Abuf + fr * 264 + kc * 32 + fk8);
            s8v a1 = *(const s8v*)(Abuf + (16 + fr) * 264 + kc * 32 + fk8);
            acc[0] = __builtin_amdgcn_mfma_f32_16x16x32_bf16(a0, b, acc[0], 0, 0, 0);
            acc[1] = __builtin_amdgcn_mfma_f32_16x16x32_bf16(a1, b, acc[1], 0, 0, 0);
        }
        __syncthreads();
        float bz = f1_bL[gcol];
        #pragma unroll
        for (int g = 0; g < 2; g++)
            #pragma unroll
            for (int r = 0; r < 4; r++)
                Abuf[(g * 16 + rb + r) * 264 + gcol] = f2bu(fmaxf(acc[g][r] + bz, 0.0f));
    }
    __syncthreads();

    // ---- phase 5: FFN2 + relu + residual, final write (+ restage if EMITVAL) ----
    {
        f4v acc[2] = {};
        #pragma unroll
        for (int kc = 0; kc < 8; kc++) {
            s8v b = *(const s8v*)(wf2L + (((size_t)w * 8 + kc) * 64 + l) * 8);
            s8v a0 = *(const s8v*)(Abuf + fr * 264 + kc * 32 + fk8);
            s8v a1 = *(const s8v*)(Abuf + (16 + fr) * 264 + kc * 32 + fk8);
            acc[0] = __builtin_amdgcn_mfma_f32_16x16x32_bf16(a0, b, acc[0], 0, 0, 0);
            acc[1] = __builtin_amdgcn_mfma_f32_16x16x32_bf16(a1, b, acc[1], 0, 0, 0);
        }
        if (EMITVAL) __syncthreads();       // drain Abuf reads before overwrite
        float bz = f2_bL[gcol];
        #pragma unroll
        for (int g = 0; g < 2; g++)
            #pragma unroll
            for (int r = 0; r < 4; r++) {
                float fin = v[g][r] + fmaxf(acc[g][r] + bz, 0.0f);
                tgt[(size_t)(m0 + g * 16 + rb + r) * 256 + gcol] = fin;
                if (EMITVAL) Abuf[(g * 16 + rb + r) * 264 + gcol] = f2bu(fin);
            }
    }
    if (EMITVAL) {
        __syncthreads();
        // ---- phase 6: next layer's value projection from in-LDS tgt ----
        f4v acc[2] = {};
        #pragma unroll
        for (int kc = 0; kc < 8; kc++) {
            s8v b = *(const s8v*)(wvalN + (((size_t)w * 8 + kc) * 64 + l) * 8);
            s8v a0 = *(const s8v*)(Abuf + fr * 264 + kc * 32 + fk8);
            s8v a1 = *(const s8v*)(Abuf + (16 + fr) * 264 + kc * 32 + fk8);
            acc[0] = __builtin_amdgcn_mfma_f32_16x16x32_bf16(a0, b, acc[0], 0, 0, 0);
            acc[1] = __builtin_amdgcn_mfma_f32_16x16x32_bf16(a1, b, acc[1], 0, 0, 0);
        }
        float bz = val_bN[gcol];
        #pragma unroll
        for (int g = 0; g < 2; g++)
            #pragma unroll
            for (int r = 0; r < 4; r++)
                valueOut[(size_t)(m0 + g * 16 + rb + r) * 256 + gcol] = f2bu(acc[g][r] + bz);
    }
}

extern "C" void kernel_launch(void* const* d_in, const int* in_sizes, int n_in,
                              void* d_out, int out_size, void* d_ws, size_t ws_size,
                              hipStream_t stream) {
    const float* feat0 = (const float*)d_in[0];
    const float* feat1 = (const float*)d_in[1];
    const float* qemb  = (const float*)d_in[2];
    const float* ref_w = (const float*)d_in[3];
    const float* ref_b = (const float*)d_in[4];
    const float* fl    = (const float*)d_in[5];
    const float* ln1_g = (const float*)d_in[6];
    const float* ln1_b = (const float*)d_in[7];
    const float* off_w = (const float*)d_in[8];
    const float* off_b = (const float*)d_in[9];
    const float* aw_w  = (const float*)d_in[10];
    const float* aw_b  = (const float*)d_in[11];
    const float* val_w = (const float*)d_in[12];
    const float* val_b = (const float*)d_in[13];
    const float* out_w = (const float*)d_in[14];
    const float* out_b = (const float*)d_in[15];
    const float* ln2_g = (const float*)d_in[16];
    const float* ln2_b = (const float*)d_in[17];
    const float* f1_w  = (const float*)d_in[18];
    const float* f1_b  = (const float*)d_in[19];
    const float* f2_w  = (const float*)d_in[20];
    const float* f2_b  = (const float*)d_in[21];

    float* tgt = (float*)d_out;
    float* ws = (float*)d_ws;
    float* pos     = ws;                                     // 1,048,576 f32
    float* refp    = pos + 1048576;                          // 8,192 f32
    float* bOA     = refp + 8192;                            // 768 f32
    ushort* value01= (ushort*)(bOA + 768);                   // MT*512
    ushort* valueS0= value01 + (size_t)MT * 512;             // MT*256
    ushort* valueS1= valueS0 + (size_t)MT * 256;             // MT*256
    ushort* wval01 = valueS1 + (size_t)MT * 256;             // 131072
    ushort* wvalS  = wval01 + 131072;                        // 131072
    ushort* woffaw = wvalS + 131072;                         // 196608
    ushort* wout   = woffaw + 196608;                        // 262144
    ushort* wf1    = wout + 262144;                          // 262144
    ushort* wf2    = wf1 + 262144;                           // 262144
    ushort* fused_bf = wf2 + 262144;                         // MT*256

    setup_kernel<<<5940, 256, 0, stream>>>(qemb, ref_w, ref_b, feat0, feat1, fl,
                                           val_w, off_w, aw_w, out_w, f1_w, f2_w,
                                           off_b, aw_b,
                                           pos, refp, tgt,
                                           wval01, wvalS, woffaw, wout, wf1, wf2,
                                           bOA, fused_bf);

    // value projections for both cross layers: [MT,512] bf16
    pgemm<<<dim3(256, 2), 1024, 0, stream>>>(fused_bf, wval01, val_b, value01, 512);

    // L0 (cross)
    layer_kernel<0, 0><<<256, 1024, 0, stream>>>(
        tgt, qemb, ln1_g, ln1_b,
        woffaw, bOA, value01, 512, refp,
        wout, out_b, ln2_g, ln2_b,
        wf1, f1_b, wf2, f2_b,
        nullptr, nullptr, nullptr);
    // L1 (cross, emit value for L2)
    layer_kernel<0, 1><<<256, 1024, 0, stream>>>(
        tgt, qemb, ln1_g + CC, ln1_b + CC,
        woffaw + 49152, bOA + 192, value01 + 256, 512, refp,
        wout + 65536, out_b + CC, ln2_g + CC, ln2_b + CC,
        wf1 + 65536, f1_b + CC, wf2 + 65536, f2_b + CC,
        wvalS, val_b + 2 * CC, valueS0);
    // L2 (self, emit value for L3)
    layer_kernel<1, 1><<<256, 1024, 0, stream>>>(
        tgt, pos, nullptr, nullptr,
        woffaw + 2 * 49152, bOA + 2 * 192, valueS0, 256, refp,
        wout + 2 * 65536, out_b + 2 * CC, ln2_g + 2 * CC, ln2_b + 2 * CC,
        wf1 + 2 * 65536, f1_b + 2 * CC, wf2 + 2 * 65536, f2_b + 2 * CC,
        wvalS + 65536, val_b + 3 * CC, valueS1);
    // L3 (self)
    layer_kernel<1, 0><<<256, 1024, 0, stream>>>(
        tgt, pos, nullptr, nullptr,
        woffaw + 3 * 49152, bOA + 3 * 192, valueS1, 256, refp,
        wout + 3 * 65536, out_b + 3 * CC, ln2_g + 3 * CC, ln2_b + 3 * CC,
        wf1 + 3 * 65536, f1_b + 3 * CC, wf2 + 3 * 65536, f2_b + 3 * CC,
        nullptr, nullptr, nullptr);
}